// Round 4
// baseline (254.158 us; speedup 1.0000x reference)
//
#include <hip/hip_runtime.h>
#include <math.h>

// Problem constants (from reference)
#define NPTS   131072
#define DIMC   256      // 16*16 output channels per point
#define YD     9
#define NPATHS 96
#define NPATH0 32
#define HID    64
#define NREG   65       // <= HID+1 relu-sign regions over t in [0,inf)
#define QSTR   18       // coeffs per (region, c): 9 for t*Y, 9 for Y

typedef float f32x4 __attribute__((ext_vector_type(4)));

// ws layout (floats):
//   Q    : [NREG][DIMC][QSTR] = 299520
//   xflip: [HID]
//   k2   : [DIMC]

// ---------------------------------------------------------------------------
// Kernel A: per-region coefficient precompute, coalesced version.
// Grid = NREG*4 blocks of 256. Block (j, cq) computes Q[j][cq*64 .. cq*64+63].
//   region sign pattern: sigma_h(j) = base_h XOR (rank_h < j)
//   sv[w] = sum_h sigma a_h W2[h,w];  sc[w] = sum_h sigma b_h W2[h,w] + b2[w]
//   Q[j][c][y]   = sum_w M1[(c*9+y)*96 + w] * sv[w]   (coeff of t*Y_y)
//   Q[j][c][9+y] = sum_w M1[(c*9+y)*96 + w] * sc[w]   (coeff of Y_y)
// Wave computes one (c,y) row per iteration: coalesced M1 row load + butterfly.
// ---------------------------------------------------------------------------
__global__ __launch_bounds__(256) void precompute_kernel(
    const float* __restrict__ W1, const float* __restrict__ b1,
    const float* __restrict__ W2, const float* __restrict__ b2,
    const float* __restrict__ M1, const float* __restrict__ M2,
    const float* __restrict__ wgt,
    float* __restrict__ Q, float* __restrict__ xout, float* __restrict__ k2out)
{
    const int j   = blockIdx.x >> 2;
    const int cq  = blockIdx.x & 3;
    const int tid = threadIdx.x;
    __shared__ __align__(16) float sx[HID];
    __shared__ __align__(16) float sa[HID], sb[HID];
    __shared__ __align__(16) float ssa[HID], ssb[HID];
    __shared__ __align__(16) float sv[NPATHS], sc[NPATHS];

    if (tid < HID) {
        float a = W1[tid], b = b1[tid];
        sa[tid] = a; sb[tid] = b;
        // knot in (0,inf) exists iff a,b have opposite (strict) signs
        bool flips = (a > 0.f && b < 0.f) || (a < 0.f && b > 0.f);
        sx[tid] = flips ? (-b / a) : __builtin_inff();
    }
    __syncthreads();
    if (tid < HID) {
        float a = sa[tid], b = sb[tid], xh = sx[tid];
        int rank = 0;
        for (int k = 0; k < HID; ++k) {
            float xk = sx[k];
            rank += (xk < xh || (xk == xh && k < tid)) ? 1 : 0;
        }
        bool base = (b > 0.f) || (b == 0.f && a > 0.f);  // pattern at t->0+
        bool sig  = base ^ (rank < j);
        ssa[tid] = sig ? a : 0.f;
        ssb[tid] = sig ? b : 0.f;
    }
    __syncthreads();
    if (tid < NPATHS) {
        float vv = 0.f, cc = 0.f;
        for (int h = 0; h < HID; ++h) {
            float w2 = W2[h * NPATHS + tid];   // coalesced across tid
            vv += ssa[h] * w2;
            cc += ssb[h] * w2;
        }
        sv[tid] = vv;
        sc[tid] = cc + b2[tid];
    }
    __syncthreads();

    {   // wave-per-row coalesced dot + butterfly reduce (both dots together)
        const int wid  = tid >> 6;
        const int lane = tid & 63;
        const float s_v  = sv[lane];
        const float s_c  = sc[lane];
        const float s_v2 = (lane < 32) ? sv[64 + lane] : 0.f;
        const float s_c2 = (lane < 32) ? sc[64 + lane] : 0.f;
        const int cbase = cq * 64 + wid * 16;          // 16 channels per wave
        const float* m1base = M1 + (size_t)(cbase * YD) * NPATHS;
        for (int idx = 0; idx < 16 * YD; ++idx) {      // idx = c_local*9 + y
            const float* row = m1base + (size_t)idx * NPATHS;
            float m1 = row[lane];
            float m2 = (lane < 32) ? row[64 + lane] : 0.f;
            float mP = m1 * s_v + m2 * s_v2;
            float mD = m1 * s_c + m2 * s_c2;
            #pragma unroll
            for (int off = 32; off; off >>= 1) {
                mP += __shfl_xor(mP, off, 64);
                mD += __shfl_xor(mD, off, 64);
            }
            if (lane == 0) {
                const int c = cbase + idx / 9;
                const int y = idx % 9;
                float* qrow = Q + ((size_t)j * DIMC + c) * QSTR;
                qrow[y]     = mP;
                qrow[9 + y] = mD;
            }
        }
    }

    if (j == 0 && cq == 0) {
        if (tid < HID) xout[tid] = sx[tid];
        float s = 0.f;
        #pragma unroll
        for (int k = 0; k < NPATH0; ++k) s += M2[tid * NPATH0 + k] * wgt[k];
        k2out[tid] = s;
    }
}

// ---------------------------------------------------------------------------
// Kernel B: main. Block = 256 threads, 64 points.
// Phase 1 (tid<64 = wave 0): t, Y, region id jj, mask -> 20-float LDS line
// per point; ballot-detect whether all 64 points share one region.
// Phase 2: thread=(cg,pg), cg in [0,64) handles c-quad cg*4, pg splits the
// 64 points into 4 chunks of 16.
// NOTE: p-loop unroll capped at 2 — full unroll hoisted ~80 ds_reads and
// blew VGPRs into scratch (R1-R3 at ~200us total).
// ---------------------------------------------------------------------------
__global__ __launch_bounds__(256) void main_kernel(
    const float* __restrict__ r, const float* __restrict__ Q,
    const float* __restrict__ xflip, const float* __restrict__ k2,
    float* __restrict__ out)
{
    __shared__ __align__(16) float qArr[64 * 20];
    __shared__ int sUni, sJJ0;
    const int tid = threadIdx.x;
    const int n0  = blockIdx.x * 64;

    if (tid < 64) {
        const int n = n0 + tid;
        float rx = r[(size_t)n * 3 + 0];
        float ry = r[(size_t)n * 3 + 1];
        float rz = r[(size_t)n * 3 + 2];
        float t  = sqrtf(rx * rx + ry * ry + rz * rz);
        float rcp = 1.f / fmaxf(t, 1e-12f);
        float ux = rx * rcp, uy = ry * rcp, uz = rz * rcp;
        const float c0 = 0.28209479177387814f;
        const float c1 = 0.4886025119029199f;
        const float c2 = 1.0925484305920792f;
        float Y[9];
        Y[0] = c0;
        Y[1] = c1 * uy;
        Y[2] = c1 * uz;
        Y[3] = c1 * ux;
        Y[4] = c2 * ux * uy;
        Y[5] = c2 * uy * uz;
        Y[6] = 0.31539156525252005f * (3.f * uz * uz - 1.f);
        Y[7] = c2 * ux * uz;
        Y[8] = 0.5462742152960396f * (ux * ux - uy * uy);
        int jj = 0;
        for (int h = 0; h < HID; ++h) jj += (xflip[h] < t) ? 1 : 0;
        float* q = qArr + tid * 20;
        #pragma unroll
        for (int y = 0; y < 9; ++y) { q[y] = t * Y[y]; q[9 + y] = Y[y]; }
        q[18] = (float)jj;
        q[19] = (t > 0.f) ? 1.f : 0.f;
        // wave 0 is fully active here: detect region-uniformity
        int jj0 = __shfl(jj, 0, 64);
        unsigned long long bal = __ballot(jj == jj0);
        if (tid == 0) { sUni = (bal == 0xFFFFFFFFFFFFFFFFULL) ? 1 : 0; sJJ0 = jj0; }
    }
    __syncthreads();

    const int cg  = tid & 63;
    const int pg  = tid >> 6;
    const int c0i = cg * 4;
    const float4 k2v = *(const float4*)(k2 + c0i);
    const int pbeg = pg * 16;

    if (sUni) {
        // ---- hot path: one region for the whole block ----
        const float4* cb = (const float4*)(Q + ((size_t)sJJ0 * DIMC + c0i) * QSTR);
        float cfs[72];
        #pragma unroll
        for (int v = 0; v < 18; ++v) {
            float4 t4 = cb[v];
            cfs[v * 4 + 0] = t4.x; cfs[v * 4 + 1] = t4.y;
            cfs[v * 4 + 2] = t4.z; cfs[v * 4 + 3] = t4.w;
        }
        #pragma unroll 2
        for (int p = pbeg; p < pbeg + 16; ++p) {
            const float4* qv = (const float4*)(qArr + p * 20);
            float4 a0 = qv[0], a1 = qv[1], a2 = qv[2], a3 = qv[3], a4 = qv[4];
            float qs[18] = { a0.x, a0.y, a0.z, a0.w,  a1.x, a1.y, a1.z, a1.w,
                             a2.x, a2.y, a2.z, a2.w,  a3.x, a3.y, a3.z, a3.w,
                             a4.x, a4.y };
            float acc0 = 0.f, acc1 = 0.f, acc2 = 0.f, acc3 = 0.f;
            #pragma unroll
            for (int i = 0; i < 18; ++i) {
                acc0 += qs[i] * cfs[0 * 18 + i];
                acc1 += qs[i] * cfs[1 * 18 + i];
                acc2 += qs[i] * cfs[2 * 18 + i];
                acc3 += qs[i] * cfs[3 * 18 + i];
            }
            const bool msk = (a4.w != 0.f);
            f32x4 o;
            o.x = msk ? acc0 : k2v.x;
            o.y = msk ? acc1 : k2v.y;
            o.z = msk ? acc2 : k2v.z;
            o.w = msk ? acc3 : k2v.w;
            __builtin_nontemporal_store(o, (f32x4*)(out + (size_t)(n0 + p) * DIMC + c0i));
        }
    } else {
        // ---- fallback: mixed regions in block (general correctness) ----
        float cfs[72];
        int curj = -1;
        for (int p = pbeg; p < pbeg + 16; ++p) {
            const float4* qv = (const float4*)(qArr + p * 20);
            float4 a0 = qv[0], a1 = qv[1], a2 = qv[2], a3 = qv[3], a4 = qv[4];
            int jj = (int)a4.z;
            if (jj != curj) {               // wave-uniform (p identical in-wave)
                curj = jj;
                const float4* cb = (const float4*)(Q + ((size_t)jj * DIMC + c0i) * QSTR);
                #pragma unroll
                for (int v = 0; v < 18; ++v) {
                    float4 t4 = cb[v];
                    cfs[v * 4 + 0] = t4.x; cfs[v * 4 + 1] = t4.y;
                    cfs[v * 4 + 2] = t4.z; cfs[v * 4 + 3] = t4.w;
                }
            }
            float qs[18] = { a0.x, a0.y, a0.z, a0.w,  a1.x, a1.y, a1.z, a1.w,
                             a2.x, a2.y, a2.z, a2.w,  a3.x, a3.y, a3.z, a3.w,
                             a4.x, a4.y };
            float acc0 = 0.f, acc1 = 0.f, acc2 = 0.f, acc3 = 0.f;
            #pragma unroll
            for (int i = 0; i < 18; ++i) {
                acc0 += qs[i] * cfs[0 * 18 + i];
                acc1 += qs[i] * cfs[1 * 18 + i];
                acc2 += qs[i] * cfs[2 * 18 + i];
                acc3 += qs[i] * cfs[3 * 18 + i];
            }
            const bool msk = (a4.w != 0.f);
            float4 o;
            o.x = msk ? acc0 : k2v.x;
            o.y = msk ? acc1 : k2v.y;
            o.z = msk ? acc2 : k2v.z;
            o.w = msk ? acc3 : k2v.w;
            *(float4*)(out + (size_t)(n0 + p) * DIMC + c0i) = o;
        }
    }
}

extern "C" void kernel_launch(void* const* d_in, const int* in_sizes, int n_in,
                              void* d_out, int out_size, void* d_ws, size_t ws_size,
                              hipStream_t stream)
{
    const float* r   = (const float*)d_in[0];
    const float* M1  = (const float*)d_in[1];
    const float* M2  = (const float*)d_in[2];
    const float* wgt = (const float*)d_in[3];
    const float* W1  = (const float*)d_in[4];
    const float* b1  = (const float*)d_in[5];
    const float* W2  = (const float*)d_in[6];
    const float* b2  = (const float*)d_in[7];
    float* out = (float*)d_out;

    float* ws = (float*)d_ws;
    float* Q  = ws;
    float* xf = ws + (size_t)NREG * DIMC * QSTR;
    float* k2 = xf + HID;

    precompute_kernel<<<NREG * 4, 256, 0, stream>>>(W1, b1, W2, b2, M1, M2, wgt, Q, xf, k2);
    main_kernel<<<NPTS / 64, 256, 0, stream>>>(r, Q, xf, k2, out);
}

// Round 5
// 182.125 us; speedup vs baseline: 1.3955x; 1.3955x over previous
//
#include <hip/hip_runtime.h>
#include <math.h>

// Problem constants (from reference)
#define NPTS   131072
#define DIMC   256      // 16*16 output channels per point
#define YD     9
#define NPATHS 96
#define NPATH0 32
#define HID    64
#define NREG   65       // <= HID+1 relu-sign regions over t in [0,inf)
#define QSTR   18       // coeffs per (region, c): 9 for t*Y, 9 for Y

typedef float f32x4 __attribute__((ext_vector_type(4)));

// ws layout (floats):
//   Q    : [NREG][DIMC][QSTR] = 299520
//   xflip: [HID]
//   k2   : [DIMC]

// ---------------------------------------------------------------------------
// Kernel A: per-region coefficient precompute (R1 structure: thread = channel,
// cache-resident uncoalesced M1 loads — M1 is 884 KB, L2/L3-hot; R4's
// butterfly-reduce version was 5x SLOWER due to serial shfl chains).
// y split 3 ways across blocks to cut per-thread latency depth.
// Grid = NREG*3. Block (j, ys) computes Q[j][*][y0..y0+2] (+9 offsets).
// ---------------------------------------------------------------------------
__global__ __launch_bounds__(256) void precompute_kernel(
    const float* __restrict__ W1, const float* __restrict__ b1,
    const float* __restrict__ W2, const float* __restrict__ b2,
    const float* __restrict__ M1, const float* __restrict__ M2,
    const float* __restrict__ wgt,
    float* __restrict__ Q, float* __restrict__ xout, float* __restrict__ k2out)
{
    const int j   = blockIdx.x / 3;
    const int ys  = blockIdx.x % 3;
    const int tid = threadIdx.x;
    __shared__ __align__(16) float sx[HID];
    __shared__ __align__(16) float sa[HID], sb[HID];
    __shared__ __align__(16) float ssa[HID], ssb[HID];
    __shared__ __align__(16) float sv[NPATHS], sc[NPATHS];

    if (tid < HID) {
        float a = W1[tid], b = b1[tid];
        sa[tid] = a; sb[tid] = b;
        // knot in (0,inf) exists iff a,b have opposite (strict) signs
        bool flips = (a > 0.f && b < 0.f) || (a < 0.f && b > 0.f);
        sx[tid] = flips ? (-b / a) : __builtin_inff();
    }
    __syncthreads();
    if (tid < HID) {
        float a = sa[tid], b = sb[tid], xh = sx[tid];
        int rank = 0;
        for (int k = 0; k < HID; ++k) {
            float xk = sx[k];
            rank += (xk < xh || (xk == xh && k < tid)) ? 1 : 0;
        }
        bool base = (b > 0.f) || (b == 0.f && a > 0.f);  // pattern at t->0+
        bool sig  = base ^ (rank < j);
        ssa[tid] = sig ? a : 0.f;
        ssb[tid] = sig ? b : 0.f;
    }
    __syncthreads();
    if (tid < NPATHS) {
        float vv = 0.f, cc = 0.f;
        for (int h = 0; h < HID; ++h) {
            float w2 = W2[h * NPATHS + tid];
            vv += ssa[h] * w2;
            cc += ssb[h] * w2;
        }
        sv[tid] = vv;
        sc[tid] = cc + b2[tid];
    }
    __syncthreads();
    {   // thread = output channel c; 3 y-values per block
        const int c  = tid;
        const int y0 = ys * 3;
        float accP[3] = {0.f, 0.f, 0.f};
        float accD[3] = {0.f, 0.f, 0.f};
        for (int w4 = 0; w4 < NPATHS / 4; ++w4) {
            float4 v4 = ((const float4*)sv)[w4];
            float4 c4 = ((const float4*)sc)[w4];
            #pragma unroll
            for (int e = 0; e < 3; ++e) {
                const float4 m4 = *(const float4*)(M1 + (size_t)(c * YD + y0 + e) * NPATHS + w4 * 4);
                accP[e] += m4.x * v4.x + m4.y * v4.y + m4.z * v4.z + m4.w * v4.w;
                accD[e] += m4.x * c4.x + m4.y * c4.y + m4.z * c4.z + m4.w * c4.w;
            }
        }
        float* qrow = Q + ((size_t)j * DIMC + c) * QSTR;
        #pragma unroll
        for (int e = 0; e < 3; ++e) {
            qrow[y0 + e]     = accP[e];
            qrow[9 + y0 + e] = accD[e];
        }
    }
    if (j == 0 && ys == 0) {
        if (tid < HID) xout[tid] = sx[tid];
        float s = 0.f;
        #pragma unroll
        for (int k = 0; k < NPATH0; ++k) s += M2[tid * NPATH0 + k] * wgt[k];
        k2out[tid] = s;
    }
}

// ---------------------------------------------------------------------------
// Kernel B: main. Block = 256 threads, 64 points.
// Phase 1 (tid<64 = wave 0): t, Y, region id jj, mask -> 20-float LDS line
// per point; ballot-detect whether all 64 points share one region.
// Phase 2: thread=(cg,pg), cg in [0,64) handles c-quad cg*4, pg splits the
// 64 points into 4 chunks of 16.
// NOTE: NO unroll pragma on the p-loop — full unroll hoisted ~80 ds_reads,
// blew VGPRs into scratch (R1-R3 ~200us). launch_bounds(256,2) caps at 256
// VGPR as a guard. Multi-wave occupancy hides DS latency instead.
// ---------------------------------------------------------------------------
__global__ __launch_bounds__(256, 2) void main_kernel(
    const float* __restrict__ r, const float* __restrict__ Q,
    const float* __restrict__ xflip, const float* __restrict__ k2,
    float* __restrict__ out)
{
    __shared__ __align__(16) float qArr[64 * 20];
    __shared__ int sUni, sJJ0;
    const int tid = threadIdx.x;
    const int n0  = blockIdx.x * 64;

    if (tid < 64) {
        const int n = n0 + tid;
        float rx = r[(size_t)n * 3 + 0];
        float ry = r[(size_t)n * 3 + 1];
        float rz = r[(size_t)n * 3 + 2];
        float t  = sqrtf(rx * rx + ry * ry + rz * rz);
        float rcp = 1.f / fmaxf(t, 1e-12f);
        float ux = rx * rcp, uy = ry * rcp, uz = rz * rcp;
        const float c0 = 0.28209479177387814f;
        const float c1 = 0.4886025119029199f;
        const float c2 = 1.0925484305920792f;
        float Y[9];
        Y[0] = c0;
        Y[1] = c1 * uy;
        Y[2] = c1 * uz;
        Y[3] = c1 * ux;
        Y[4] = c2 * ux * uy;
        Y[5] = c2 * uy * uz;
        Y[6] = 0.31539156525252005f * (3.f * uz * uz - 1.f);
        Y[7] = c2 * ux * uz;
        Y[8] = 0.5462742152960396f * (ux * ux - uy * uy);
        int jj = 0;
        for (int h = 0; h < HID; ++h) jj += (xflip[h] < t) ? 1 : 0;
        float* q = qArr + tid * 20;
        #pragma unroll
        for (int y = 0; y < 9; ++y) { q[y] = t * Y[y]; q[9 + y] = Y[y]; }
        q[18] = (float)jj;
        q[19] = (t > 0.f) ? 1.f : 0.f;
        // wave 0 is fully active here: detect region-uniformity
        int jj0 = __shfl(jj, 0, 64);
        unsigned long long bal = __ballot(jj == jj0);
        if (tid == 0) { sUni = (bal == 0xFFFFFFFFFFFFFFFFULL) ? 1 : 0; sJJ0 = jj0; }
    }
    __syncthreads();

    const int cg  = tid & 63;
    const int pg  = tid >> 6;
    const int c0i = cg * 4;
    const float4 k2v = *(const float4*)(k2 + c0i);
    const int pbeg = pg * 16;

    if (sUni) {
        // ---- hot path: one region for the whole block ----
        const float4* cb = (const float4*)(Q + ((size_t)sJJ0 * DIMC + c0i) * QSTR);
        float cfs[72];
        #pragma unroll
        for (int v = 0; v < 18; ++v) {
            float4 t4 = cb[v];
            cfs[v * 4 + 0] = t4.x; cfs[v * 4 + 1] = t4.y;
            cfs[v * 4 + 2] = t4.z; cfs[v * 4 + 3] = t4.w;
        }
        for (int p = pbeg; p < pbeg + 16; ++p) {
            const float4* qv = (const float4*)(qArr + p * 20);
            float4 a0 = qv[0], a1 = qv[1], a2 = qv[2], a3 = qv[3], a4 = qv[4];
            float acc0, acc1, acc2, acc3;
            acc0  = a0.x * cfs[ 0] + a0.y * cfs[ 1] + a0.z * cfs[ 2] + a0.w * cfs[ 3];
            acc0 += a1.x * cfs[ 4] + a1.y * cfs[ 5] + a1.z * cfs[ 6] + a1.w * cfs[ 7];
            acc0 += a2.x * cfs[ 8] + a2.y * cfs[ 9] + a2.z * cfs[10] + a2.w * cfs[11];
            acc0 += a3.x * cfs[12] + a3.y * cfs[13] + a3.z * cfs[14] + a3.w * cfs[15];
            acc0 += a4.x * cfs[16] + a4.y * cfs[17];
            acc1  = a0.x * cfs[18] + a0.y * cfs[19] + a0.z * cfs[20] + a0.w * cfs[21];
            acc1 += a1.x * cfs[22] + a1.y * cfs[23] + a1.z * cfs[24] + a1.w * cfs[25];
            acc1 += a2.x * cfs[26] + a2.y * cfs[27] + a2.z * cfs[28] + a2.w * cfs[29];
            acc1 += a3.x * cfs[30] + a3.y * cfs[31] + a3.z * cfs[32] + a3.w * cfs[33];
            acc1 += a4.x * cfs[34] + a4.y * cfs[35];
            acc2  = a0.x * cfs[36] + a0.y * cfs[37] + a0.z * cfs[38] + a0.w * cfs[39];
            acc2 += a1.x * cfs[40] + a1.y * cfs[41] + a1.z * cfs[42] + a1.w * cfs[43];
            acc2 += a2.x * cfs[44] + a2.y * cfs[45] + a2.z * cfs[46] + a2.w * cfs[47];
            acc2 += a3.x * cfs[48] + a3.y * cfs[49] + a3.z * cfs[50] + a3.w * cfs[51];
            acc2 += a4.x * cfs[52] + a4.y * cfs[53];
            acc3  = a0.x * cfs[54] + a0.y * cfs[55] + a0.z * cfs[56] + a0.w * cfs[57];
            acc3 += a1.x * cfs[58] + a1.y * cfs[59] + a1.z * cfs[60] + a1.w * cfs[61];
            acc3 += a2.x * cfs[62] + a2.y * cfs[63] + a2.z * cfs[64] + a2.w * cfs[65];
            acc3 += a3.x * cfs[66] + a3.y * cfs[67] + a3.z * cfs[68] + a3.w * cfs[69];
            acc3 += a4.x * cfs[70] + a4.y * cfs[71];
            const bool msk = (a4.w != 0.f);
            f32x4 o;
            o.x = msk ? acc0 : k2v.x;
            o.y = msk ? acc1 : k2v.y;
            o.z = msk ? acc2 : k2v.z;
            o.w = msk ? acc3 : k2v.w;
            __builtin_nontemporal_store(o, (f32x4*)(out + (size_t)(n0 + p) * DIMC + c0i));
        }
    } else {
        // ---- fallback: mixed regions in block (general correctness) ----
        float cfs[72];
        int curj = -1;
        for (int p = pbeg; p < pbeg + 16; ++p) {
            const float4* qv = (const float4*)(qArr + p * 20);
            float4 a0 = qv[0], a1 = qv[1], a2 = qv[2], a3 = qv[3], a4 = qv[4];
            int jj = (int)a4.z;
            if (jj != curj) {               // wave-uniform (p identical in-wave)
                curj = jj;
                const float4* cb = (const float4*)(Q + ((size_t)jj * DIMC + c0i) * QSTR);
                #pragma unroll
                for (int v = 0; v < 18; ++v) {
                    float4 t4 = cb[v];
                    cfs[v * 4 + 0] = t4.x; cfs[v * 4 + 1] = t4.y;
                    cfs[v * 4 + 2] = t4.z; cfs[v * 4 + 3] = t4.w;
                }
            }
            float qs[18] = { a0.x, a0.y, a0.z, a0.w,  a1.x, a1.y, a1.z, a1.w,
                             a2.x, a2.y, a2.z, a2.w,  a3.x, a3.y, a3.z, a3.w,
                             a4.x, a4.y };
            float acc0 = 0.f, acc1 = 0.f, acc2 = 0.f, acc3 = 0.f;
            #pragma unroll
            for (int i = 0; i < 18; ++i) {
                acc0 += qs[i] * cfs[0 * 18 + i];
                acc1 += qs[i] * cfs[1 * 18 + i];
                acc2 += qs[i] * cfs[2 * 18 + i];
                acc3 += qs[i] * cfs[3 * 18 + i];
            }
            const bool msk = (a4.w != 0.f);
            float4 o;
            o.x = msk ? acc0 : k2v.x;
            o.y = msk ? acc1 : k2v.y;
            o.z = msk ? acc2 : k2v.z;
            o.w = msk ? acc3 : k2v.w;
            *(float4*)(out + (size_t)(n0 + p) * DIMC + c0i) = o;
        }
    }
}

extern "C" void kernel_launch(void* const* d_in, const int* in_sizes, int n_in,
                              void* d_out, int out_size, void* d_ws, size_t ws_size,
                              hipStream_t stream)
{
    const float* r   = (const float*)d_in[0];
    const float* M1  = (const float*)d_in[1];
    const float* M2  = (const float*)d_in[2];
    const float* wgt = (const float*)d_in[3];
    const float* W1  = (const float*)d_in[4];
    const float* b1  = (const float*)d_in[5];
    const float* W2  = (const float*)d_in[6];
    const float* b2  = (const float*)d_in[7];
    float* out = (float*)d_out;

    float* ws = (float*)d_ws;
    float* Q  = ws;
    float* xf = ws + (size_t)NREG * DIMC * QSTR;
    float* k2 = xf + HID;

    precompute_kernel<<<NREG * 3, 256, 0, stream>>>(W1, b1, W2, b2, M1, M2, wgt, Q, xf, k2);
    main_kernel<<<NPTS / 64, 256, 0, stream>>>(r, Q, xf, k2, out);
}